// Round 3
// baseline (1396.013 us; speedup 1.0000x reference)
//
#include <hip/hip_runtime.h>

// B=4, P=8192, M=2048, K=32, C=64, IN=67(->96 pad), H=128, OC=128, Q=64
// Rows N = 262144. MFMA 16x16x32 bf16. BN1 stats computed analytically.

typedef __attribute__((ext_vector_type(8))) short s16x8;
typedef __attribute__((ext_vector_type(4))) float f32x4;

__device__ __forceinline__ unsigned short f2bf(float f) {
  unsigned int u = __float_as_uint(f);
  unsigned int r = u + 0x7fffu + ((u >> 16) & 1u);  // RNE
  return (unsigned short)(r >> 16);
}

// ---------------- feats (B,C,P) fp32 -> featsT (B,P,C) bf16 ----------------
__global__ __launch_bounds__(256) void tr_kernel(const float* __restrict__ feats,
                                                 unsigned short* __restrict__ featsT) {
  __shared__ float tile[64][65];
  const int b = blockIdx.y;
  const int p0 = blockIdx.x * 64;
  const int t = threadIdx.x;
  {
    const int pp = t & 63, c4 = t >> 6;
#pragma unroll
    for (int j = 0; j < 16; ++j) {
      int c = j * 4 + c4;
      tile[c][pp] = feats[((size_t)(b * 64 + c)) * 8192 + p0 + pp];
    }
  }
  __syncthreads();
  {
    const int cc = t & 63, p4 = t >> 6;
#pragma unroll
    for (int j = 0; j < 16; ++j) {
      int pr = j * 4 + p4;
      featsT[((size_t)(b * 8192 + p0 + pr)) * 64 + cc] = f2bf(tile[cc][pr]);
    }
  }
}

// ------------- prep: weight pack (bf16, k-contig, pad) + xyzq float4 -------------
__global__ __launch_bounds__(256) void prep_kernel(const float* __restrict__ W1,
                                                   const float* __restrict__ W2,
                                                   const float* __restrict__ Wq1,
                                                   const float* __restrict__ xyz,
                                                   unsigned short* __restrict__ W1p,
                                                   unsigned short* __restrict__ W2p,
                                                   unsigned short* __restrict__ Wq1p,
                                                   float4* __restrict__ xyzq) {
  int i = blockIdx.x * 256 + threadIdx.x;
  if (i < 13312) {  // W1p[128][104]: k<64 feats (W1[o][3+k]), k 64..66 xyz, else 0
    int o = i / 104, k = i % 104;
    float v = 0.f;
    if (k < 64) v = W1[o * 67 + 3 + k];
    else if (k < 67) v = W1[o * 67 + (k - 64)];
    W1p[i] = f2bf(v);
    return;
  }
  i -= 13312;
  if (i < 17408) {  // W2p[128][136]
    int o = i / 136, k = i % 136;
    W2p[i] = (k < 128) ? f2bf(W2[o * 128 + k]) : (unsigned short)0;
    return;
  }
  i -= 17408;
  if (i < 8704) {  // Wq1p[64][136]
    int o = i / 136, k = i % 136;
    Wq1p[i] = (k < 128) ? f2bf(Wq1[o * 128 + k]) : (unsigned short)0;
    return;
  }
  i -= 8704;
  if (i < 32768) {
    const float* q = xyz + (size_t)i * 3;
    float x = q[0], y = q[1], z = q[2];
    float4 v; v.x = x; v.y = y; v.z = z; v.w = (x * x + y * y) + z * z;
    xyzq[i] = v;
  }
}

// ---------------- selection: one WAVE per center, zero barriers ----------------
// 2048-bin histogram (ordered-uint >> 21) in swizzled LDS slots; exact tie-break
// via 64-bit (u,idx) candidates in the cutoff bin. Epilogue scatters cnt/sc and
// accumulates global d-moment sums for the analytic BN1 stats.
#define CAND2 224
__global__ __launch_bounds__(256) void sel2_kernel(const float4* __restrict__ xyzq,
    float* __restrict__ centers_out, int* __restrict__ idx_out,
    float* __restrict__ cnt, float* __restrict__ scx, float* __restrict__ scy,
    float* __restrict__ scz, float* __restrict__ dstats) {
  const int t = threadIdx.x, lane = t & 63, w = t >> 6;
  const int b = blockIdx.y;
  const int mIdx = blockIdx.x * 4 + w;  // grid.x = 512
  __shared__ unsigned int hist[4][2048];
  __shared__ unsigned long long cand[4][CAND2];
  __shared__ int selb[4][32];
  __shared__ int ctr[4][2];
  unsigned int* H = hist[w];
#pragma unroll
  for (int j = 0; j < 32; ++j) H[j * 64 + lane] = 0;
  if (lane == 0) { ctr[w][0] = 0; ctr[w][1] = 0; }
  const int pc = (mIdx * 8191) / 2047;  // floor(linspace(0,P-1,M))
  const float4* xb = xyzq + b * 8192;
  const float4 c = xb[pc];
  if (lane == 0) {
    float* co = centers_out + ((size_t)(b * 2048 + mIdx)) * 3;
    co[0] = c.x; co[1] = c.y; co[2] = c.z;
  }
  // pass 1: histogram (bin k lives at LDS slot (k&31)*64 + (k>>5) -> conflict-free scans)
  for (int i = 0; i < 128; ++i) {
    float4 v = xb[i * 64 + lane];
    float dot = (c.x * v.x + c.y * v.y) + c.z * v.z;
    float d2 = (c.w + v.w) - 2.0f * dot;
    unsigned int u = __float_as_uint(d2);
    u = (u & 0x80000000u) ? ~u : (u | 0x80000000u);
    unsigned int key = u >> 21;
    atomicAdd(&H[(key & 31) * 64 + (key >> 5)], 1u);
  }
  // cutoff: lane owns ordered bins [lane*32, lane*32+32)
  int csum = 0;
#pragma unroll
  for (int j = 0; j < 32; ++j) csum += (int)H[j * 64 + lane];
  int incl = csum;
#pragma unroll
  for (int d = 1; d < 64; d <<= 1) {
    int v2 = __shfl_up(incl, d);
    if (lane >= d) incl += v2;
  }
  int before = incl - csum;
  unsigned long long mk = __ballot((before < 32) && (incl >= 32));
  int cutlane = __ffsll((unsigned long long)mk) - 1;
  int cum = before, cutloc = lane * 32 + 31;
  bool fnd = false;
#pragma unroll
  for (int j = 0; j < 32; ++j) {
    int cv = (int)H[j * 64 + lane];
    if (!fnd) {
      if (cum + cv >= 32) { cutloc = lane * 32 + j; fnd = true; }
      else cum += cv;
    }
  }
  const unsigned int cutbin = (unsigned int)__shfl(cutloc, cutlane);
  // pass 2: collect definite picks + cutoff-bin candidates
  for (int i = 0; i < 128; ++i) {
    int p = i * 64 + lane;
    float4 v = xb[p];
    float dot = (c.x * v.x + c.y * v.y) + c.z * v.z;
    float d2 = (c.w + v.w) - 2.0f * dot;
    unsigned int u = __float_as_uint(d2);
    u = (u & 0x80000000u) ? ~u : (u | 0x80000000u);
    unsigned int key = u >> 21;
    if (key < cutbin) {
      int pos = atomicAdd(&ctr[w][0], 1);
      selb[w][pos] = p;
    } else if (key == cutbin) {
      int pos = atomicAdd(&ctr[w][1], 1);
      if (pos < CAND2) cand[w][pos] = ((unsigned long long)u << 32) | (unsigned int)p;
    }
  }
  const int nsel = ctr[w][0];
  const int need = 32 - nsel;
  const int nc = min(ctr[w][1], CAND2);
  volatile unsigned long long* vc = cand[w];
  for (int r = 0; r < need; ++r) {
    unsigned long long best = ~0ull;
    int bs = -1;
#pragma unroll
    for (int base = 0; base < CAND2; base += 64) {
      int j = base + lane;
      if (j < nc) {
        unsigned long long v = vc[j];
        if (v < best) { best = v; bs = j; }
      }
    }
#pragma unroll
    for (int d = 32; d; d >>= 1) {
      unsigned long long ob = __shfl_xor(best, d);
      int os = __shfl_xor(bs, d);
      if (ob < best) { best = ob; bs = os; }
    }
    if (lane == 0) {
      selb[w][nsel + r] = (int)(best & 0xffffffffu);
      cand[w][bs] = ~0ull;
    }
  }
  if (lane < 32)
    idx_out[(size_t)(b * 2048 + mIdx) * 32 + lane] = selb[w][lane];
  // epilogue: scatter cnt/sc, accumulate global d-moments (for analytic BN1 stats)
  float dx = 0, dy = 0, dz = 0, xx = 0, yy = 0, zz = 0, xy = 0, xz = 0, yz = 0;
  if (lane < 32) {
    int psel = selb[w][lane];
    float4 v = xb[psel];
    dx = v.x - c.x; dy = v.y - c.y; dz = v.z - c.z;
    xx = dx * dx; yy = dy * dy; zz = dz * dz;
    xy = dx * dy; xz = dx * dz; yz = dy * dz;
    int gp = b * 8192 + psel;
    atomicAdd(&cnt[gp], 1.0f);
    atomicAdd(&scx[gp], c.x);
    atomicAdd(&scy[gp], c.y);
    atomicAdd(&scz[gp], c.z);
  }
  float vals[9] = {dx, dy, dz, xx, yy, zz, xy, xz, yz};
#pragma unroll
  for (int k = 0; k < 9; ++k) {
#pragma unroll
    for (int d = 1; d < 64; d <<= 1) vals[k] += __shfl_xor(vals[k], d);
  }
  if (lane == 0) {
#pragma unroll
    for (int k = 0; k < 9; ++k) atomicAdd(&dstats[k], vals[k]);
  }
}

// ---------------- weighted Gram for analytic BN1 stats ----------------
// Sff[c1][c2] = sum_p cnt_p f[c1][p] f[c2][p];  Sfd[c1][d] = sum_p f[c1][p] e_d[p]
// with e = cnt*x - sc;  Fbar[c1] = sum_p cnt_p f[c1][p].
__global__ __launch_bounds__(256) void gram_kernel(const float* __restrict__ feats,
    const float4* __restrict__ xyzq, const float* __restrict__ cnt,
    const float* __restrict__ scx, const float* __restrict__ scy,
    const float* __restrict__ scz, float* __restrict__ Sff,
    float* __restrict__ Sfd, float* __restrict__ Fbar) {
  const int t = threadIdx.x;
  const int b = blockIdx.y, p0 = blockIdx.x * 128;  // grid (64,4)
  __shared__ float fT[128][68];
  __shared__ float cw_s[128], e_s[3][128];
#pragma unroll
  for (int j = 0; j < 32; ++j) {
    int idx = j * 256 + t;
    int cch = idx >> 7, pp = idx & 127;
    fT[pp][cch] = feats[((size_t)(b * 64 + cch)) * 8192 + p0 + pp];
  }
  if (t < 128) {
    int gp = b * 8192 + p0 + t;
    float cw = cnt[gp];
    cw_s[t] = cw;
    float4 v = xyzq[gp];
    e_s[0][t] = cw * v.x - scx[gp];
    e_s[1][t] = cw * v.y - scy[gp];
    e_s[2][t] = cw * v.z - scz[gp];
  }
  __syncthreads();
  const int c1 = (t >> 4) * 4, c2 = (t & 15) * 4;
  const int aux = t & 3;
  const bool doaux = ((t & 15) < 4);
  float acc[4][4] = {};
  float accA[4] = {};
  for (int pp = 0; pp < 128; ++pp) {
    float cw = cw_s[pp];
    float4 f1 = *(const float4*)&fT[pp][c1];
    float4 f2 = *(const float4*)&fT[pp][c2];
    float f1a[4] = {f1.x, f1.y, f1.z, f1.w};
    float f2a[4] = {f2.x, f2.y, f2.z, f2.w};
#pragma unroll
    for (int i = 0; i < 4; ++i) {
      float wsc = f1a[i] * cw;
#pragma unroll
      for (int j = 0; j < 4; ++j) acc[i][j] += wsc * f2a[j];
    }
    if (doaux) {
      float mult = (aux < 3) ? e_s[aux][pp] : cw;
#pragma unroll
      for (int i = 0; i < 4; ++i) accA[i] += f1a[i] * mult;
    }
  }
#pragma unroll
  for (int i = 0; i < 4; ++i)
#pragma unroll
    for (int j = 0; j < 4; ++j) atomicAdd(&Sff[(c1 + i) * 64 + c2 + j], acc[i][j]);
  if (doaux) {
#pragma unroll
    for (int i = 0; i < 4; ++i) {
      if (aux < 3) atomicAdd(&Sfd[(c1 + i) * 3 + aux], accA[i]);
      else atomicAdd(&Fbar[c1 + i], accA[i]);
    }
  }
}

// ---------------- finalize analytic BN1 stats: stats[c]=Sum Y1, stats[128+c]=Sum Y1^2 ----------------
__global__ __launch_bounds__(256) void fin_kernel(const float* __restrict__ W1,
    const float* __restrict__ b1, const float* __restrict__ Sff,
    const float* __restrict__ Sfd, const float* __restrict__ Fbar,
    const float* __restrict__ dstats, float* __restrict__ stats) {
  __shared__ float sS[4096], sFd[192], sFb[64], sD[16];
  const int t = threadIdx.x;
  for (int j = t; j < 4096; j += 256) sS[j] = Sff[j];
  if (t < 192) sFd[t] = Sfd[t];
  if (t < 64) sFb[t] = Fbar[t];
  if (t < 9) sD[t] = dstats[t];
  __syncthreads();
  const int c = t >> 1, h = t & 1;
  float wf[64];
#pragma unroll
  for (int i = 0; i < 64; ++i) wf[i] = W1[c * 67 + 3 + i];
  const float wx0 = W1[c * 67], wx1 = W1[c * 67 + 1], wx2 = W1[c * 67 + 2];
  float qacc = 0.f;
  for (int i = h * 32; i < h * 32 + 32; ++i) {
    float rd = 0.f;
    const float4* row = (const float4*)&sS[i * 64];
#pragma unroll
    for (int j4 = 0; j4 < 16; ++j4) {
      float4 v = row[j4];
      rd += v.x * wf[j4 * 4] + v.y * wf[j4 * 4 + 1] + v.z * wf[j4 * 4 + 2] + v.w * wf[j4 * 4 + 3];
    }
    rd += 2.f * (sFd[i * 3] * wx0 + sFd[i * 3 + 1] * wx1 + sFd[i * 3 + 2] * wx2);
    qacc += wf[i] * rd;
  }
  qacc += __shfl_xor(qacc, 1);
  if (h == 0) {
    const float N = 262144.f;
    float lin = 0.f;
#pragma unroll
    for (int i = 0; i < 64; ++i) lin += wf[i] * sFb[i];
    lin += wx0 * sD[0] + wx1 * sD[1] + wx2 * sD[2];
    float bb = b1[c];
    float Sy = lin + bb * N;
    float dd = wx0 * wx0 * sD[3] + wx1 * wx1 * sD[4] + wx2 * wx2 * sD[5]
             + 2.f * (wx0 * wx1 * sD[6] + wx0 * wx2 * sD[7] + wx1 * wx2 * sD[8]);
    float Sy2 = qacc + dd + 2.f * bb * lin + bb * bb * N;
    stats[c] = Sy;
    stats[128 + c] = Sy2;
  }
}

// ---------------- MFMA MLP: STAGE 2 = BN2-stats pass, STAGE 3 = final ----------------
// Block = 64 rows x 512 thr. G1 A-frags loaded DIRECTLY from global (featsT rows are
// already in MFMA-A layout). LDS regions: R1 = W1 -> (sred | Wq1), R2h = W2 half
// (restaged) -> epilogue scratch, R3 = A2 -> A3.
template <int STAGE>
__global__ __launch_bounds__(512) void mlp_kernel(
    const float* __restrict__ xyz, const unsigned short* __restrict__ featsT,
    const int* __restrict__ idxbuf, const float* __restrict__ centers,
    const unsigned short* __restrict__ W1p_g, const float* __restrict__ b1,
    const float* __restrict__ g1, const float* __restrict__ be1,
    const unsigned short* __restrict__ W2p_g, const float* __restrict__ b2,
    const float* __restrict__ g2, const float* __restrict__ be2,
    const unsigned short* __restrict__ Wq1p_g, const float* __restrict__ bq1,
    const float* __restrict__ Wq2, const float* __restrict__ bq2,
    float* __restrict__ stats, float* __restrict__ out_agg) {
  const int t = threadIdx.x;
  const int T = blockIdx.x;
  const int G0 = T * 2;
  const int b = G0 >> 11;

  __shared__ __align__(16) unsigned short R1[13312];  // 26624 B
  __shared__ __align__(16) unsigned short R2h[8704];  // 17408 B
  __shared__ __align__(16) unsigned short R3[8704];   // 17408 B
  __shared__ float sc1a[128], sh1a[128], sc2a[128], sh2a[128];
  float* sredS = (float*)R1;          // stage2 stats overlay (R1 free after G1)
  float* sredQ = (float*)R1 + 512;
  float* sv2 = (float*)R2h;           // stage3 epilogue overlay (R2h free after G2)
  float* wv = (float*)R2h + 128;
  float* agg = (float*)R2h + 192;

  const int lane = t & 63, wid = t >> 6;
  const int m = lane & 15, q = lane >> 4;
  const int rw = wid & 3, cw = wid >> 2;

  // stage W1 -> R1, W2 half0 -> R2h
  for (int i = t; i < 1664; i += 512) ((s16x8*)R1)[i] = ((const s16x8*)W1p_g)[i];
  for (int i = t; i < 1088; i += 512) ((s16x8*)R2h)[i] = ((const s16x8*)W2p_g)[i];

  const float invN = 1.0f / 262144.0f;
  if (t < 128) {
    float mu = stats[t] * invN;
    float var = stats[128 + t] * invN - mu * mu;
    float s = g1[t] * rsqrtf(var + 1e-5f);
    sc1a[t] = s;
    sh1a[t] = (b1[t] - mu) * s + be1[t];
    if (STAGE == 3) {
      float mu2 = stats[256 + t] * invN;
      float var2 = stats[384 + t] * invN - mu2 * mu2;
      float s2 = g2[t] * rsqrtf(var2 + 1e-5f);
      sc2a[t] = s2;
      sh2a[t] = (b2[t] - mu2) * s2 + be2[t];
    }
  }

  // A-frag gather: per-lane direct global loads (issued before b0 to overlap staging)
  const int r = rw * 16 + m;
  const int g = G0 + (r >> 5);
  const int p = idxbuf[(size_t)g * 32 + (r & 31)];
  const unsigned short* fr = featsT + ((size_t)(b * 8192) + p) * 64;
  s16x8 a0 = *(const s16x8*)(fr + q * 8);
  s16x8 a1 = *(const s16x8*)(fr + 32 + q * 8);
  s16x8 a2 = (s16x8){0, 0, 0, 0, 0, 0, 0, 0};
  if (q == 0) {
    const float* cp = centers + (size_t)g * 3;
    const float* qp = xyz + ((size_t)(b * 8192) + p) * 3;
    a2[0] = (short)f2bf(qp[0] - cp[0]);
    a2[1] = (short)f2bf(qp[1] - cp[1]);
    a2[2] = (short)f2bf(qp[2] - cp[2]);
  }
  __syncthreads();  // b0: weights + consts ready

  // ---- G1: 96 -> 128 ----
  f32x4 acc[4];
#pragma unroll
  for (int nt = 0; nt < 4; ++nt) acc[nt] = (f32x4){0.f, 0.f, 0.f, 0.f};
#pragma unroll
  for (int kb = 0; kb < 3; ++kb) {
    s16x8 a = (kb == 0) ? a0 : ((kb == 1) ? a1 : a2);
#pragma unroll
    for (int nt = 0; nt < 4; ++nt) {
      s16x8 bf = *(const s16x8*)(R1 + (cw * 64 + nt * 16 + m) * 104 + kb * 32 + q * 8);
      acc[nt] = __builtin_amdgcn_mfma_f32_16x16x32_bf16(a, bf, acc[nt], 0, 0, 0);
    }
  }
  // BN1+ReLU -> A2 (R3)
#pragma unroll
  for (int nt = 0; nt < 4; ++nt) {
    int ch = cw * 64 + nt * 16 + m;
    float s = sc1a[ch], o = sh1a[ch];
#pragma unroll
    for (int r4 = 0; r4 < 4; ++r4)
      R3[(rw * 16 + q * 4 + r4) * 136 + ch] = f2bf(fmaxf(acc[nt][r4] * s + o, 0.f));
  }
  __syncthreads();  // b1: A2 ready; R1 reads done

  // ---- G2: 128 -> 128 in two 64-col halves ----
  float fl[2][2][4];
  const int aoff2 = (rw * 16 + m) * 136 + q * 8;
  for (int h2 = 0; h2 < 2; ++h2) {
    if (h2 == 1) {
      __syncthreads();  // b2: G2h0's R2h reads done
      for (int i = t; i < 1088; i += 512) ((s16x8*)R2h)[i] = ((const s16x8*)W2p_g)[1088 + i];
      if (STAGE == 3) {
        for (int i = t; i < 1088; i += 512) ((s16x8*)R1)[i] = ((const s16x8*)Wq1p_g)[i];
      }
      __syncthreads();  // b3
    }
    f32x4 bacc[2];
#pragma unroll
    for (int nt = 0; nt < 2; ++nt) bacc[nt] = (f32x4){0.f, 0.f, 0.f, 0.f};
#pragma unroll
    for (int kb = 0; kb < 4; ++kb) {
      s16x8 a = *(const s16x8*)(R3 + aoff2 + kb * 32);
#pragma unroll
      for (int nt = 0; nt < 2; ++nt) {
        s16x8 bf = *(const s16x8*)(R2h + (cw * 32 + nt * 16 + m) * 136 + kb * 32 + q * 8);
        bacc[nt] = __builtin_amdgcn_mfma_f32_16x16x32_bf16(a, bf, bacc[nt], 0, 0, 0);
      }
    }
    if (STAGE == 2) {
#pragma unroll
      for (int nt = 0; nt < 2; ++nt) {
        int chl = cw * 32 + nt * 16 + m;
        float bb = b2[h2 * 64 + chl];
        float s = 0.f, sq = 0.f;
#pragma unroll
        for (int r4 = 0; r4 < 4; ++r4) {
          float y = bacc[nt][r4] + bb;
          s += y; sq += y * y;
        }
        s += __shfl_xor(s, 16); sq += __shfl_xor(sq, 16);
        s += __shfl_xor(s, 32); sq += __shfl_xor(sq, 32);
        if (q == 0) { sredS[chl * 4 + rw] = s; sredQ[chl * 4 + rw] = sq; }
      }
      __syncthreads();
      if (t < 64) {
        float ss = sredS[t * 4] + sredS[t * 4 + 1] + sredS[t * 4 + 2] + sredS[t * 4 + 3];
        float qq = sredQ[t * 4] + sredQ[t * 4 + 1] + sredQ[t * 4 + 2] + sredQ[t * 4 + 3];
        atomicAdd(&stats[256 + h2 * 64 + t], ss);
        atomicAdd(&stats[384 + h2 * 64 + t], qq);
      }
      __syncthreads();
    } else {
      // BN2+ReLU -> fp32 regs only (A3 written after both halves finish reading R3)
#pragma unroll
      for (int nt = 0; nt < 2; ++nt) {
        int ch = h2 * 64 + cw * 32 + nt * 16 + m;
        float s = sc2a[ch], o = sh2a[ch];
#pragma unroll
        for (int r4 = 0; r4 < 4; ++r4)
          fl[h2][nt][r4] = fmaxf(bacc[nt][r4] * s + o, 0.f);
      }
    }
  }
  if (STAGE == 2) return;

  __syncthreads();  // b4: all R3(A2)/R2h reads done
  // write A3 (FL bf16) into R3
#pragma unroll
  for (int h2 = 0; h2 < 2; ++h2)
#pragma unroll
    for (int nt = 0; nt < 2; ++nt) {
      int ch = h2 * 64 + cw * 32 + nt * 16 + m;
#pragma unroll
      for (int r4 = 0; r4 < 4; ++r4)
        R3[(rw * 16 + q * 4 + r4) * 136 + ch] = f2bf(fl[h2][nt][r4]);
    }
  __syncthreads();  // b5: A3 + Wq1 (staged at b2-b3) ready

  // ---- Q: 128 -> 64, ReLU, dot Wq2 -> scores ----
  {
    f32x4 qacc[2];
#pragma unroll
    for (int nt = 0; nt < 2; ++nt) qacc[nt] = (f32x4){0.f, 0.f, 0.f, 0.f};
#pragma unroll
    for (int kb = 0; kb < 4; ++kb) {
      s16x8 a = *(const s16x8*)(R3 + aoff2 + kb * 32);
#pragma unroll
      for (int nt = 0; nt < 2; ++nt) {
        s16x8 bf = *(const s16x8*)(R1 + (cw * 32 + nt * 16 + m) * 136 + kb * 32 + q * 8);
        qacc[nt] = __builtin_amdgcn_mfma_f32_16x16x32_bf16(a, bf, qacc[nt], 0, 0, 0);
      }
    }
    int qc0 = cw * 32 + m, qc1 = qc0 + 16;
    float ba0 = bq1[qc0], ba1 = bq1[qc1];
    float w0 = Wq2[qc0], w1 = Wq2[qc1];
    float part[4];
#pragma unroll
    for (int r4 = 0; r4 < 4; ++r4) {
      float v0 = fmaxf(qacc[0][r4] + ba0, 0.f);
      float v1 = fmaxf(qacc[1][r4] + ba1, 0.f);
      part[r4] = v0 * w0 + v1 * w1;
    }
#pragma unroll
    for (int d = 1; d < 16; d <<= 1) {
#pragma unroll
      for (int r4 = 0; r4 < 4; ++r4) part[r4] += __shfl_xor(part[r4], d);
    }
    if (m == 0) {
#pragma unroll
      for (int r4 = 0; r4 < 4; ++r4) sv2[(rw * 16 + q * 4 + r4) * 2 + cw] = part[r4];
    }
  }
  __syncthreads();  // b6
  if (t < 64) {
    float x = sv2[t * 2] + sv2[t * 2 + 1] + bq2[0];
    float mx = x;
#pragma unroll
    for (int d = 16; d; d >>= 1) mx = fmaxf(mx, __shfl_xor(mx, d, 32));
    float e = expf(x - mx);
    float ssum = e;
#pragma unroll
    for (int d = 16; d; d >>= 1) ssum += __shfl_xor(ssum, d, 32);
    wv[t] = e / ssum;
  }
  __syncthreads();  // b7
  // fp32 weighted aggregation from C-frag registers
  {
    float wreg[4];
#pragma unroll
    for (int r4 = 0; r4 < 4; ++r4) wreg[r4] = wv[rw * 16 + q * 4 + r4];
    const int gl = rw >> 1, rwpar = rw & 1;
#pragma unroll
    for (int h2 = 0; h2 < 2; ++h2)
#pragma unroll
      for (int nt = 0; nt < 2; ++nt) {
        float pv = 0.f;
#pragma unroll
        for (int r4 = 0; r4 < 4; ++r4) pv += wreg[r4] * fl[h2][nt][r4];
        pv += __shfl_xor(pv, 16);
        pv += __shfl_xor(pv, 32);
        if (q == 0) {
          int ch = h2 * 64 + cw * 32 + nt * 16 + m;
          agg[(gl * 128 + ch) * 2 + rwpar] = pv;
        }
      }
  }
  __syncthreads();  // b8
  if (t < 256) {
    int gl = t >> 7, ch = t & 127;
    float v = agg[(gl * 128 + ch) * 2] + agg[(gl * 128 + ch) * 2 + 1];
    out_agg[((size_t)(b * 128 + ch)) * 2048 + ((G0 + gl) & 2047)] = v;
  }
}

extern "C" void kernel_launch(void* const* d_in, const int* in_sizes, int n_in,
                              void* d_out, int out_size, void* d_ws, size_t ws_size,
                              hipStream_t stream) {
  const float* xyz   = (const float*)d_in[0];
  const float* feats = (const float*)d_in[1];
  const float* W1    = (const float*)d_in[2];
  const float* b1    = (const float*)d_in[3];
  const float* g1    = (const float*)d_in[4];
  const float* be1   = (const float*)d_in[5];
  const float* W2    = (const float*)d_in[6];
  const float* b2    = (const float*)d_in[7];
  const float* g2    = (const float*)d_in[8];
  const float* be2   = (const float*)d_in[9];
  const float* Wq1   = (const float*)d_in[10];
  const float* bq1   = (const float*)d_in[11];
  const float* Wq2   = (const float*)d_in[12];
  const float* bq2   = (const float*)d_in[13];

  float* outp    = (float*)d_out;
  float* centers = outp;           // (4,2048,3)
  float* out_agg = outp + 24576;   // (4,128,2048)

  // ws layout (~6.4 MB)
  char* base = (char*)d_ws;
  unsigned short* featsT = (unsigned short*)base;                  // 4,194,304
  float4* xyzq  = (float4*)(base + 4194304);                       //   524,288
  int*    idxb  = (int*)(base + 4718592);                          // 1,048,576
  unsigned short* W1p  = (unsigned short*)(base + 5767168);        //    26,624
  unsigned short* W2p  = (unsigned short*)(base + 5793792);        //    34,816
  unsigned short* Wq1p = (unsigned short*)(base + 5828608);        //    17,408
  float* stats  = (float*)(base + 5846016);   // zero region start
  float* dstats = stats + 512;
  float* Fbar   = stats + 528;
  float* Sfd    = stats + 592;
  float* Sff    = stats + 784;
  float* cntp   = stats + 4880;
  float* scx    = cntp + 32768;
  float* scy    = scx + 32768;
  float* scz    = scy + 32768;

  hipMemsetAsync(stats, 0, 543808, stream);
  prep_kernel<<<282, 256, 0, stream>>>(W1, W2, Wq1, xyz, W1p, W2p, Wq1p, xyzq);
  tr_kernel<<<dim3(128, 4), 256, 0, stream>>>(feats, featsT);
  sel2_kernel<<<dim3(512, 4), 256, 0, stream>>>(xyzq, centers, idxb, cntp, scx, scy, scz, dstats);
  gram_kernel<<<dim3(64, 4), 256, 0, stream>>>(feats, xyzq, cntp, scx, scy, scz, Sff, Sfd, Fbar);
  fin_kernel<<<1, 256, 0, stream>>>(W1, b1, Sff, Sfd, Fbar, dstats, stats);
  mlp_kernel<2><<<4096, 512, 0, stream>>>(xyz, featsT, idxb, centers,
                                          W1p, b1, g1, be1, W2p, b2, g2, be2,
                                          Wq1p, bq1, Wq2, bq2, stats, out_agg);
  mlp_kernel<3><<<4096, 512, 0, stream>>>(xyz, featsT, idxb, centers,
                                          W1p, b1, g1, be1, W2p, b2, g2, be2,
                                          Wq1p, bq1, Wq2, bq2, stats, out_agg);
}

// Round 4
// 799.150 us; speedup vs baseline: 1.7469x; 1.7469x over previous
//
#include <hip/hip_runtime.h>

// B=4, P=8192, M=2048, K=32, C=64, IN=67(->96 pad), H=128, OC=128, Q=64
// Rows N = 262144. MFMA 16x16x32 bf16. BN1 stats computed analytically.

typedef __attribute__((ext_vector_type(8))) short s16x8;
typedef __attribute__((ext_vector_type(4))) float f32x4;

__device__ __forceinline__ unsigned short f2bf(float f) {
  unsigned int u = __float_as_uint(f);
  unsigned int r = u + 0x7fffu + ((u >> 16) & 1u);  // RNE
  return (unsigned short)(r >> 16);
}

// ---------------- feats (B,C,P) fp32 -> featsT (B,P,C) bf16 ----------------
__global__ __launch_bounds__(256) void tr_kernel(const float* __restrict__ feats,
                                                 unsigned short* __restrict__ featsT) {
  __shared__ float tile[64][65];
  const int b = blockIdx.y;
  const int p0 = blockIdx.x * 64;
  const int t = threadIdx.x;
  {
    const int pp = t & 63, c4 = t >> 6;
#pragma unroll
    for (int j = 0; j < 16; ++j) {
      int c = j * 4 + c4;
      tile[c][pp] = feats[((size_t)(b * 64 + c)) * 8192 + p0 + pp];
    }
  }
  __syncthreads();
  {
    const int cc = t & 63, p4 = t >> 6;
#pragma unroll
    for (int j = 0; j < 16; ++j) {
      int pr = j * 4 + p4;
      featsT[((size_t)(b * 8192 + p0 + pr)) * 64 + cc] = f2bf(tile[cc][pr]);
    }
  }
}

// ------------- prep: weight pack (bf16, k-contig, pad) + xyzq float4 -------------
__global__ __launch_bounds__(256) void prep_kernel(const float* __restrict__ W1,
                                                   const float* __restrict__ W2,
                                                   const float* __restrict__ Wq1,
                                                   const float* __restrict__ xyz,
                                                   unsigned short* __restrict__ W1p,
                                                   unsigned short* __restrict__ W2p,
                                                   unsigned short* __restrict__ Wq1p,
                                                   float4* __restrict__ xyzq) {
  int i = blockIdx.x * 256 + threadIdx.x;
  if (i < 13312) {  // W1p[128][104]: k<64 feats (W1[o][3+k]), k 64..66 xyz, else 0
    int o = i / 104, k = i % 104;
    float v = 0.f;
    if (k < 64) v = W1[o * 67 + 3 + k];
    else if (k < 67) v = W1[o * 67 + (k - 64)];
    W1p[i] = f2bf(v);
    return;
  }
  i -= 13312;
  if (i < 17408) {  // W2p[128][136]
    int o = i / 136, k = i % 136;
    W2p[i] = (k < 128) ? f2bf(W2[o * 128 + k]) : (unsigned short)0;
    return;
  }
  i -= 17408;
  if (i < 8704) {  // Wq1p[64][136]
    int o = i / 136, k = i % 136;
    Wq1p[i] = (k < 128) ? f2bf(Wq1[o * 128 + k]) : (unsigned short)0;
    return;
  }
  i -= 8704;
  if (i < 32768) {
    const float* q = xyz + (size_t)i * 3;
    float x = q[0], y = q[1], z = q[2];
    float4 v; v.x = x; v.y = y; v.z = z; v.w = (x * x + y * y) + z * z;
    xyzq[i] = v;
  }
}

// ---------------- selection: 512-thr block, 16 points/thread in regs, 16 centers ----------------
// Histogram select on ordered-uint >> 20 (4096 bins); exact tie-break in cutoff bin.
// Waves 1..7 clear the histogram for the next center while wave 0 runs the tie-break.
#define CANDMAX 512
__global__ __launch_bounds__(512, 4) void sel3_kernel(const float4* __restrict__ xyzq,
    float* __restrict__ centers_out, int* __restrict__ idx_out) {
  const int t = threadIdx.x, lane = t & 63, wid = t >> 6;
  const int b = blockIdx.y;
  const int m0 = blockIdx.x * 16;  // grid.x = 128
  __shared__ unsigned int hist[4096];
  __shared__ unsigned long long cand[CANDMAX];
  __shared__ float4 cc4[16];
  __shared__ int selb[32];
  __shared__ int ctrl[4];
  __shared__ int wsum[8];

  const float4* xb = xyzq + (size_t)b * 8192;
  float4 pt[16];
#pragma unroll
  for (int i = 0; i < 16; ++i) pt[i] = xb[i * 512 + t];

  if (t < 16) {
    int mIdx = m0 + t;
    int pc = (mIdx * 8191) / 2047;  // floor(linspace(0,P-1,M))
    float4 c = xb[pc];
    cc4[t] = c;
    float* co = centers_out + ((size_t)(b * 2048 + mIdx)) * 3;
    co[0] = c.x; co[1] = c.y; co[2] = c.z;
  }
  for (int j = t; j < 4096; j += 512) hist[j] = 0;
  if (t == 0) { ctrl[0] = 0; ctrl[1] = 0; }
  __syncthreads();

  for (int ci = 0; ci < 16; ++ci) {
    const float4 c = cc4[ci];
    // pass 1: histogram
#pragma unroll
    for (int i = 0; i < 16; ++i) {
      float dot = (c.x * pt[i].x + c.y * pt[i].y) + c.z * pt[i].z;
      float d2 = (c.w + pt[i].w) - 2.0f * dot;
      unsigned int u = __float_as_uint(d2);
      u = (u & 0x80000000u) ? ~u : (u | 0x80000000u);
      atomicAdd(&hist[u >> 20], 1u);
    }
    __syncthreads();  // B1
    // block scan over 4096 ordered bins; thread owns bins [t*8, t*8+8)
    const int base = t * 8;
    int csum = 0;
#pragma unroll
    for (int j = 0; j < 8; ++j) csum += (int)hist[base + j];
    int incl = csum;
#pragma unroll
    for (int d = 1; d < 64; d <<= 1) {
      int v = __shfl_up(incl, d);
      if (lane >= d) incl += v;
    }
    if (lane == 63) wsum[wid] = incl;
    __syncthreads();  // B2
    int woff = 0;
    for (int i = 0; i < wid; ++i) woff += wsum[i];
    int excl = woff + incl - csum;
    if (excl < 32 && excl + csum >= 32) {  // unique crossing chunk
      int cum = excl, binsel = base + 7;
      for (int j = 0; j < 8; ++j) {
        int cv = (int)hist[base + j];
        if (cum + cv >= 32) { binsel = base + j; break; }
        cum += cv;
      }
      ctrl[2] = binsel;
    }
    __syncthreads();  // B3
    const unsigned int cutbin = (unsigned int)ctrl[2];
    // pass 2: collect definite picks + cutoff-bin candidates
#pragma unroll
    for (int i = 0; i < 16; ++i) {
      float dot = (c.x * pt[i].x + c.y * pt[i].y) + c.z * pt[i].z;
      float d2 = (c.w + pt[i].w) - 2.0f * dot;
      unsigned int u = __float_as_uint(d2);
      u = (u & 0x80000000u) ? ~u : (u | 0x80000000u);
      unsigned int key = u >> 20;
      if (key < cutbin) {
        int pos = atomicAdd(&ctrl[0], 1);
        selb[pos] = i * 512 + t;
      } else if (key == cutbin) {
        int pos = atomicAdd(&ctrl[1], 1);
        if (pos < CANDMAX) cand[pos] = ((unsigned long long)u << 32) | (unsigned int)(i * 512 + t);
      }
    }
    __syncthreads();  // B4
    if (t < 64) {
      // wave 0: exact tie-break by (d2_bits, idx) ascending
      const int nsel = ctrl[0];
      const int need = 32 - nsel;
      const int nc = min(ctrl[1], CANDMAX);
      volatile unsigned long long* vc = cand;
      for (int r = 0; r < need; ++r) {
        unsigned long long best = ~0ull;
        int bs = -1;
#pragma unroll
        for (int bb = 0; bb < CANDMAX; bb += 64) {
          int j = bb + lane;
          if (j < nc) {
            unsigned long long v = vc[j];
            if (v < best) { best = v; bs = j; }
          }
        }
#pragma unroll
        for (int d = 32; d; d >>= 1) {
          unsigned long long ob = __shfl_xor(best, d);
          int os = __shfl_xor(bs, d);
          if (ob < best) { best = ob; bs = os; }
        }
        if (lane == 0) {
          selb[nsel + r] = (int)(best & 0xffffffffu);
          cand[bs] = ~0ull;
        }
      }
    } else {
      // waves 1..7: clear hist for next center (hist unused by tie-break)
      for (int j = t - 64; j < 4096; j += 448) hist[j] = 0;
    }
    __syncthreads();  // B5
    if (t < 32) idx_out[(size_t)(b * 2048 + m0 + ci) * 32 + t] = selb[t];
    if (t == 0) { ctrl[0] = 0; ctrl[1] = 0; }
    __syncthreads();  // B6
  }
}

// ---------------- cnt/sc scatter + d-moments via LDS (no global float atomics) ----------------
// grid = 16 blocks: (batch b = blk>>2, point-quarter = blk&3). Accumulates
// cnt[p], sum-of-center-x/y/z[p] in LDS for its 2048-point range, flushes with
// plain stores; d-moment partials wave-reduced then 9 atomics/wave.
__global__ __launch_bounds__(1024) void cnt_kernel(const float4* __restrict__ xyzq,
    const float* __restrict__ centers, const int* __restrict__ idxb,
    float* __restrict__ cnt, float* __restrict__ scx, float* __restrict__ scy,
    float* __restrict__ scz, float* __restrict__ dstats) {
  const int t = threadIdx.x;
  const int b = blockIdx.x >> 2, quar = blockIdx.x & 3;
  const int pbase = quar * 2048;
  __shared__ float L[4][2048];
  for (int j = t; j < 8192; j += 1024) ((float*)L)[j] = 0.f;
  __syncthreads();
  float m9[9] = {0.f, 0.f, 0.f, 0.f, 0.f, 0.f, 0.f, 0.f, 0.f};
  for (int i = 0; i < 64; ++i) {
    int e = i * 1024 + t;  // (g,k) flat index within batch
    int p = idxb[b * 65536 + e];
    if (p >= pbase && p < pbase + 2048) {
      int g = e >> 5;
      const float* cp = centers + ((size_t)(b * 2048 + g)) * 3;
      float cx = cp[0], cy = cp[1], cz = cp[2];
      float4 v = xyzq[(size_t)b * 8192 + p];
      int l = p - pbase;
      atomicAdd(&L[0][l], 1.f);
      atomicAdd(&L[1][l], cx);
      atomicAdd(&L[2][l], cy);
      atomicAdd(&L[3][l], cz);
      float dx = v.x - cx, dy = v.y - cy, dz = v.z - cz;
      m9[0] += dx; m9[1] += dy; m9[2] += dz;
      m9[3] += dx * dx; m9[4] += dy * dy; m9[5] += dz * dz;
      m9[6] += dx * dy; m9[7] += dx * dz; m9[8] += dy * dz;
    }
  }
#pragma unroll
  for (int k = 0; k < 9; ++k) {
#pragma unroll
    for (int d = 1; d < 64; d <<= 1) m9[k] += __shfl_xor(m9[k], d);
  }
  if ((t & 63) == 0) {
#pragma unroll
    for (int k = 0; k < 9; ++k) atomicAdd(&dstats[k], m9[k]);
  }
  __syncthreads();
  for (int j = t; j < 2048; j += 1024) {
    int gp = b * 8192 + pbase + j;
    cnt[gp] = L[0][j];
    scx[gp] = L[1][j];
    scy[gp] = L[2][j];
    scz[gp] = L[3][j];
  }
}

// ---------------- weighted Gram for analytic BN1 stats ----------------
// Sff[c1][c2] = sum_p cnt_p f[c1][p] f[c2][p];  Sfd[c1][d] = sum_p f[c1][p] e_d[p]
// with e = cnt*x - sc;  Fbar[c1] = sum_p cnt_p f[c1][p].  grid (16,4), 4 chunks.
__global__ __launch_bounds__(256) void gram_kernel(const float* __restrict__ feats,
    const float4* __restrict__ xyzq, const float* __restrict__ cnt,
    const float* __restrict__ scx, const float* __restrict__ scy,
    const float* __restrict__ scz, float* __restrict__ Sff,
    float* __restrict__ Sfd, float* __restrict__ Fbar) {
  const int t = threadIdx.x;
  const int b = blockIdx.y;
  __shared__ float fT[128][68];
  __shared__ float cw_s[128], e_s[3][128];
  const int c1 = (t >> 4) * 4, c2 = (t & 15) * 4;
  const int aux = t & 3;
  const bool doaux = ((t & 15) < 4);
  float acc[4][4] = {};
  float accA[4] = {};
  for (int chunk = 0; chunk < 4; ++chunk) {
    const int p0 = blockIdx.x * 512 + chunk * 128;
    __syncthreads();
#pragma unroll
    for (int j = 0; j < 32; ++j) {
      int idx = j * 256 + t;
      int cch = idx >> 7, pp = idx & 127;
      fT[pp][cch] = feats[((size_t)(b * 64 + cch)) * 8192 + p0 + pp];
    }
    if (t < 128) {
      int gp = b * 8192 + p0 + t;
      float cw = cnt[gp];
      cw_s[t] = cw;
      float4 v = xyzq[gp];
      e_s[0][t] = cw * v.x - scx[gp];
      e_s[1][t] = cw * v.y - scy[gp];
      e_s[2][t] = cw * v.z - scz[gp];
    }
    __syncthreads();
    for (int pp = 0; pp < 128; ++pp) {
      float cw = cw_s[pp];
      float4 f1 = *(const float4*)&fT[pp][c1];
      float4 f2 = *(const float4*)&fT[pp][c2];
      float f1a[4] = {f1.x, f1.y, f1.z, f1.w};
      float f2a[4] = {f2.x, f2.y, f2.z, f2.w};
#pragma unroll
      for (int i = 0; i < 4; ++i) {
        float wsc = f1a[i] * cw;
#pragma unroll
        for (int j = 0; j < 4; ++j) acc[i][j] += wsc * f2a[j];
      }
      if (doaux) {
        float mult = (aux < 3) ? e_s[aux][pp] : cw;
#pragma unroll
        for (int i = 0; i < 4; ++i) accA[i] += f1a[i] * mult;
      }
    }
  }
#pragma unroll
  for (int i = 0; i < 4; ++i)
#pragma unroll
    for (int j = 0; j < 4; ++j) atomicAdd(&Sff[(c1 + i) * 64 + c2 + j], acc[i][j]);
  if (doaux) {
#pragma unroll
    for (int i = 0; i < 4; ++i) {
      if (aux < 3) atomicAdd(&Sfd[(c1 + i) * 3 + aux], accA[i]);
      else atomicAdd(&Fbar[c1 + i], accA[i]);
    }
  }
}

// ---------------- finalize analytic BN1 stats: stats[c]=Sum Y1, stats[128+c]=Sum Y1^2 ----------------
__global__ __launch_bounds__(256) void fin_kernel(const float* __restrict__ W1,
    const float* __restrict__ b1, const float* __restrict__ Sff,
    const float* __restrict__ Sfd, const float* __restrict__ Fbar,
    const float* __restrict__ dstats, float* __restrict__ stats) {
  __shared__ float sS[4096], sFd[192], sFb[64], sD[16];
  const int t = threadIdx.x;
  for (int j = t; j < 4096; j += 256) sS[j] = Sff[j];
  if (t < 192) sFd[t] = Sfd[t];
  if (t < 64) sFb[t] = Fbar[t];
  if (t < 9) sD[t] = dstats[t];
  __syncthreads();
  const int c = t >> 1, h = t & 1;
  float wf[64];
#pragma unroll
  for (int i = 0; i < 64; ++i) wf[i] = W1[c * 67 + 3 + i];
  const float wx0 = W1[c * 67], wx1 = W1[c * 67 + 1], wx2 = W1[c * 67 + 2];
  float qacc = 0.f;
  for (int i = h * 32; i < h * 32 + 32; ++i) {
    float rd = 0.f;
    const float4* row = (const float4*)&sS[i * 64];
#pragma unroll
    for (int j4 = 0; j4 < 16; ++j4) {
      float4 v = row[j4];
      rd += v.x * wf[j4 * 4] + v.y * wf[j4 * 4 + 1] + v.z * wf[j4 * 4 + 2] + v.w * wf[j4 * 4 + 3];
    }
    rd += 2.f * (sFd[i * 3] * wx0 + sFd[i * 3 + 1] * wx1 + sFd[i * 3 + 2] * wx2);
    qacc += wf[i] * rd;
  }
  qacc += __shfl_xor(qacc, 1);
  if (h == 0) {
    const float N = 262144.f;
    float lin = 0.f;
#pragma unroll
    for (int i = 0; i < 64; ++i) lin += wf[i] * sFb[i];
    lin += wx0 * sD[0] + wx1 * sD[1] + wx2 * sD[2];
    float bb = b1[c];
    float Sy = lin + bb * N;
    float dd = wx0 * wx0 * sD[3] + wx1 * wx1 * sD[4] + wx2 * wx2 * sD[5]
             + 2.f * (wx0 * wx1 * sD[6] + wx0 * wx2 * sD[7] + wx1 * wx2 * sD[8]);
    float Sy2 = qacc + dd + 2.f * bb * lin + bb * bb * N;
    stats[c] = Sy;
    stats[128 + c] = Sy2;
  }
}

// ---------------- MFMA MLP: STAGE 2 = BN2-stats pass, STAGE 3 = final ----------------
template <int STAGE>
__global__ __launch_bounds__(512) void mlp_kernel(
    const float* __restrict__ xyz, const unsigned short* __restrict__ featsT,
    const int* __restrict__ idxbuf, const float* __restrict__ centers,
    const unsigned short* __restrict__ W1p_g, const float* __restrict__ b1,
    const float* __restrict__ g1, const float* __restrict__ be1,
    const unsigned short* __restrict__ W2p_g, const float* __restrict__ b2,
    const float* __restrict__ g2, const float* __restrict__ be2,
    const unsigned short* __restrict__ Wq1p_g, const float* __restrict__ bq1,
    const float* __restrict__ Wq2, const float* __restrict__ bq2,
    float* __restrict__ stats, float* __restrict__ out_agg) {
  const int t = threadIdx.x;
  const int T = blockIdx.x;
  const int G0 = T * 2;
  const int b = G0 >> 11;

  __shared__ __align__(16) unsigned short R1[13312];  // 26624 B
  __shared__ __align__(16) unsigned short R2h[8704];  // 17408 B
  __shared__ __align__(16) unsigned short R3[8704];   // 17408 B
  __shared__ float sc1a[128], sh1a[128], sc2a[128], sh2a[128];
  float* sredS = (float*)R1;          // stage2 stats overlay (R1 free after G1)
  float* sredQ = (float*)R1 + 512;
  float* sv2 = (float*)R2h;           // stage3 epilogue overlay (R2h free after G2)
  float* wv = (float*)R2h + 128;
  float* agg = (float*)R2h + 192;

  const int lane = t & 63, wid = t >> 6;
  const int m = lane & 15, q = lane >> 4;
  const int rw = wid & 3, cw = wid >> 2;

  // stage W1 -> R1, W2 half0 -> R2h
  for (int i = t; i < 1664; i += 512) ((s16x8*)R1)[i] = ((const s16x8*)W1p_g)[i];
  for (int i = t; i < 1088; i += 512) ((s16x8*)R2h)[i] = ((const s16x8*)W2p_g)[i];

  const float invN = 1.0f / 262144.0f;
  if (t < 128) {
    float mu = stats[t] * invN;
    float var = stats[128 + t] * invN - mu * mu;
    float s = g1[t] * rsqrtf(var + 1e-5f);
    sc1a[t] = s;
    sh1a[t] = (b1[t] - mu) * s + be1[t];
    if (STAGE == 3) {
      float mu2 = stats[256 + t] * invN;
      float var2 = stats[384 + t] * invN - mu2 * mu2;
      float s2 = g2[t] * rsqrtf(var2 + 1e-5f);
      sc2a[t] = s2;
      sh2a[t] = (b2[t] - mu2) * s2 + be2[t];
    }
  }

  // A-frag gather: per-lane direct global loads (issued before b0 to overlap staging)
  const int r = rw * 16 + m;
  const int g = G0 + (r >> 5);
  const int p = idxbuf[(size_t)g * 32 + (r & 31)];
  const unsigned short* fr = featsT + ((size_t)(b * 8192) + p) * 64;
  s16x8 a0 = *(const s16x8*)(fr + q * 8);
  s16x8 a1 = *(const s16x8*)(fr + 32 + q * 8);
  s16x8 a2 = (s16x8){0, 0, 0, 0, 0, 0, 0, 0};
  if (q == 0) {
    const float* cp = centers + (size_t)g * 3;
    const float* qp = xyz + ((size_t)(b * 8192) + p) * 3;
    a2[0] = (short)f2bf(qp[0] - cp[0]);
    a2[1] = (short)f2bf(qp[1] - cp[1]);
    a2[2] = (short)f2bf(qp[2] - cp[2]);
  }
  __syncthreads();  // b0: weights + consts ready

  // ---- G1: 96 -> 128 ----
  f32x4 acc[4];
#pragma unroll
  for (int nt = 0; nt < 4; ++nt) acc[nt] = (f32x4){0.f, 0.f, 0.f, 0.f};
#pragma unroll
  for (int kb = 0; kb < 3; ++kb) {
    s16x8 a = (kb == 0) ? a0 : ((kb == 1) ? a1 : a2);
#pragma unroll
    for (int nt = 0; nt < 4; ++nt) {
      s16x8 bf = *(const s16x8*)(R1 + (cw * 64 + nt * 16 + m) * 104 + kb * 32 + q * 8);
      acc[nt] = __builtin_amdgcn_mfma_f32_16x16x32_bf16(a, bf, acc[nt], 0, 0, 0);
    }
  }
  // BN1+ReLU -> A2 (R3)
#pragma unroll
  for (int nt = 0; nt < 4; ++nt) {
    int ch = cw * 64 + nt * 16 + m;
    float s = sc1a[ch], o = sh1a[ch];
#pragma unroll
    for (int r4 = 0; r4 < 4; ++r4)
      R3[(rw * 16 + q * 4 + r4) * 136 + ch] = f2bf(fmaxf(acc[nt][r4] * s + o, 0.f));
  }
  __syncthreads();  // b1: A2 ready; R1 reads done

  // ---- G2: 128 -> 128 in two 64-col halves ----
  float fl[2][2][4];
  const int aoff2 = (rw * 16 + m) * 136 + q * 8;
  for (int h2 = 0; h2 < 2; ++h2) {
    if (h2 == 1) {
      __syncthreads();  // b2: G2h0's R2h reads done
      for (int i = t; i < 1088; i += 512) ((s16x8*)R2h)[i] = ((const s16x8*)W2p_g)[1088 + i];
      if (STAGE == 3) {
        for (int i = t; i < 1088; i += 512) ((s16x8*)R1)[i] = ((const s16x8*)Wq1p_g)[i];
      }
      __syncthreads();  // b3
    }
    f32x4 bacc[2];
#pragma unroll
    for (int nt = 0; nt < 2; ++nt) bacc[nt] = (f32x4){0.f, 0.f, 0.f, 0.f};
#pragma unroll
    for (int kb = 0; kb < 4; ++kb) {
      s16x8 a = *(const s16x8*)(R3 + aoff2 + kb * 32);
#pragma unroll
      for (int nt = 0; nt < 2; ++nt) {
        s16x8 bf = *(const s16x8*)(R2h + (cw * 32 + nt * 16 + m) * 136 + kb * 32 + q * 8);
        bacc[nt] = __builtin_amdgcn_mfma_f32_16x16x32_bf16(a, bf, bacc[nt], 0, 0, 0);
      }
    }
    if (STAGE == 2) {
#pragma unroll
      for (int nt = 0; nt < 2; ++nt) {
        int chl = cw * 32 + nt * 16 + m;
        float bb = b2[h2 * 64 + chl];
        float s = 0.f, sq = 0.f;
#pragma unroll
        for (int r4 = 0; r4 < 4; ++r4) {
          float y = bacc[nt][r4] + bb;
          s += y; sq += y * y;
        }
        s += __shfl_xor(s, 16); sq += __shfl_xor(sq, 16);
        s += __shfl_xor(s, 32); sq += __shfl_xor(sq, 32);
        if (q == 0) { sredS[chl * 4 + rw] = s; sredQ[chl * 4 + rw] = sq; }
      }
      __syncthreads();
      if (t < 64) {
        float ss = sredS[t * 4] + sredS[t * 4 + 1] + sredS[t * 4 + 2] + sredS[t * 4 + 3];
        float qq = sredQ[t * 4] + sredQ[t * 4 + 1] + sredQ[t * 4 + 2] + sredQ[t * 4 + 3];
        atomicAdd(&stats[256 + h2 * 64 + t], ss);
        atomicAdd(&stats[384 + h2 * 64 + t], qq);
      }
      __syncthreads();
    } else {
#pragma unroll
      for (int nt = 0; nt < 2; ++nt) {
        int ch = h2 * 64 + cw * 32 + nt * 16 + m;
        float s = sc2a[ch], o = sh2a[ch];
#pragma unroll
        for (int r4 = 0; r4 < 4; ++r4)
          fl[h2][nt][r4] = fmaxf(bacc[nt][r4] * s + o, 0.f);
      }
    }
  }
  if (STAGE == 2) return;

  __syncthreads();  // b4: all R3(A2)/R2h reads done
#pragma unroll
  for (int h2 = 0; h2 < 2; ++h2)
#pragma unroll
    for (int nt = 0; nt < 2; ++nt) {
      int ch = h2 * 64 + cw * 32 + nt * 16 + m;
#pragma unroll
      for (int r4 = 0; r4 < 4; ++r4)
        R3[(rw * 16 + q * 4 + r4) * 136 + ch] = f2bf(fl[h2][nt][r4]);
    }
  __syncthreads();  // b5: A3 + Wq1 ready

  // ---- Q: 128 -> 64, ReLU, dot Wq2 -> scores ----
  {
    f32x4 qacc[2];
#pragma unroll
    for (int nt = 0; nt < 2; ++nt) qacc[nt] = (f32x4){0.f, 0.f, 0.f, 0.f};
#pragma unroll
    for (int kb = 0; kb < 4; ++kb) {
      s16x8 a = *(const s16x8*)(R3 + aoff2 + kb * 32);
#pragma unroll
      for (int nt = 0; nt < 2; ++nt) {
        s16x8 bf = *(const s16x8*)(R1 + (cw * 32 + nt * 16 + m) * 136 + kb * 32 + q * 8);
        qacc[nt] = __builtin_amdgcn_mfma_f32_16x16x32_bf16(a, bf, qacc[nt], 0, 0, 0);
      }
    }
    int qc0 = cw * 32 + m, qc1 = qc0 + 16;
    float ba0 = bq1[qc0], ba1 = bq1[qc1];
    float w0 = Wq2[qc0], w1 = Wq2[qc1];
    float part[4];
#pragma unroll
    for (int r4 = 0; r4 < 4; ++r4) {
      float v0 = fmaxf(qacc[0][r4] + ba0, 0.f);
      float v1 = fmaxf(qacc[1][r4] + ba1, 0.f);
      part[r4] = v0 * w0 + v1 * w1;
    }
#pragma unroll
    for (int d = 1; d < 16; d <<= 1) {
#pragma unroll
      for (int r4 = 0; r4 < 4; ++r4) part[r4] += __shfl_xor(part[r4], d);
    }
    if (m == 0) {
#pragma unroll
      for (int r4 = 0; r4 < 4; ++r4) sv2[(rw * 16 + q * 4 + r4) * 2 + cw] = part[r4];
    }
  }
  __syncthreads();  // b6
  if (t < 64) {
    float x = sv2[t * 2] + sv2[t * 2 + 1] + bq2[0];
    float mx = x;
#pragma unroll
    for (int d = 16; d; d >>= 1) mx = fmaxf(mx, __shfl_xor(mx, d, 32));
    float e = expf(x - mx);
    float ssum = e;
#pragma unroll
    for (int d = 16; d; d >>= 1) ssum += __shfl_xor(ssum, d, 32);
    wv[t] = e / ssum;
  }
  __syncthreads();  // b7
  {
    float wreg[4];
#pragma unroll
    for (int r4 = 0; r4 < 4; ++r4) wreg[r4] = wv[rw * 16 + q * 4 + r4];
    const int gl = rw >> 1, rwpar = rw & 1;
#pragma unroll
    for (int h2 = 0; h2 < 2; ++h2)
#pragma unroll
      for (int nt = 0; nt < 2; ++nt) {
        float pv = 0.f;
#pragma unroll
        for (int r4 = 0; r4 < 4; ++r4) pv += wreg[r4] * fl[h2][nt][r4];
        pv += __shfl_xor(pv, 16);
        pv += __shfl_xor(pv, 32);
        if (q == 0) {
          int ch = h2 * 64 + cw * 32 + nt * 16 + m;
          agg[(gl * 128 + ch) * 2 + rwpar] = pv;
        }
      }
  }
  __syncthreads();  // b8
  if (t < 256) {
    int gl = t >> 7, ch = t & 127;
    float v = agg[(gl * 128 + ch) * 2] + agg[(gl * 128 + ch) * 2 + 1];
    out_agg[((size_t)(b * 128 + ch)) * 2048 + ((G0 + gl) & 2047)] = v;
  }
}

extern "C" void kernel_launch(void* const* d_in, const int* in_sizes, int n_in,
                              void* d_out, int out_size, void* d_ws, size_t ws_size,
                              hipStream_t stream) {
  const float* xyz   = (const float*)d_in[0];
  const float* feats = (const float*)d_in[1];
  const float* W1    = (const float*)d_in[2];
  const float* b1    = (const float*)d_in[3];
  const float* g1    = (const float*)d_in[4];
  const float* be1   = (const float*)d_in[5];
  const float* W2    = (const float*)d_in[6];
  const float* b2    = (const float*)d_in[7];
  const float* g2    = (const float*)d_in[8];
  const float* be2   = (const float*)d_in[9];
  const float* Wq1   = (const float*)d_in[10];
  const float* bq1   = (const float*)d_in[11];
  const float* Wq2   = (const float*)d_in[12];
  const float* bq2   = (const float*)d_in[13];

  float* outp    = (float*)d_out;
  float* centers = outp;           // (4,2048,3)
  float* out_agg = outp + 24576;   // (4,128,2048)

  // ws layout (~6.4 MB)
  char* base = (char*)d_ws;
  unsigned short* featsT = (unsigned short*)base;                  // 4,194,304
  float4* xyzq  = (float4*)(base + 4194304);                       //   524,288
  int*    idxb  = (int*)(base + 4718592);                          // 1,048,576
  unsigned short* W1p  = (unsigned short*)(base + 5767168);        //    26,624
  unsigned short* W2p  = (unsigned short*)(base + 5793792);        //    34,816
  unsigned short* Wq1p = (unsigned short*)(base + 5828608);        //    17,408
  float* stats  = (float*)(base + 5846016);   // zero region start (4880 floats)
  float* dstats = stats + 512;
  float* Fbar   = stats + 528;
  float* Sfd    = stats + 592;
  float* Sff    = stats + 784;
  float* cntp   = stats + 4880;               // fully overwritten by cnt_kernel
  float* scx    = cntp + 32768;
  float* scy    = scx + 32768;
  float* scz    = scy + 32768;

  hipMemsetAsync(stats, 0, 19520, stream);
  prep_kernel<<<282, 256, 0, stream>>>(W1, W2, Wq1, xyz, W1p, W2p, Wq1p, xyzq);
  tr_kernel<<<dim3(128, 4), 256, 0, stream>>>(feats, featsT);
  sel3_kernel<<<dim3(128, 4), 512, 0, stream>>>(xyzq, centers, idxb);
  cnt_kernel<<<16, 1024, 0, stream>>>(xyzq, centers, idxb, cntp, scx, scy, scz, dstats);
  gram_kernel<<<dim3(16, 4), 256, 0, stream>>>(feats, xyzq, cntp, scx, scy, scz, Sff, Sfd, Fbar);
  fin_kernel<<<1, 256, 0, stream>>>(W1, b1, Sff, Sfd, Fbar, dstats, stats);
  mlp_kernel<2><<<4096, 512, 0, stream>>>(xyz, featsT, idxb, centers,
                                          W1p, b1, g1, be1, W2p, b2, g2, be2,
                                          Wq1p, bq1, Wq2, bq2, stats, out_agg);
  mlp_kernel<3><<<4096, 512, 0, stream>>>(xyz, featsT, idxb, centers,
                                          W1p, b1, g1, be1, W2p, b2, g2, be2,
                                          Wq1p, bq1, Wq2, bq2, stats, out_agg);
}

// Round 5
// 648.565 us; speedup vs baseline: 2.1525x; 1.2322x over previous
//
#include <hip/hip_runtime.h>

// B=4, P=8192, M=2048, K=32, C=64, IN=67(->96 pad), H=128, OC=128, Q=64
// Rows N = 262144. MFMA 16x16x32 bf16. BN1 stats computed analytically.

typedef __attribute__((ext_vector_type(8))) short s16x8;
typedef __attribute__((ext_vector_type(4))) float f32x4;

__device__ __forceinline__ unsigned short f2bf(float f) {
  unsigned int u = __float_as_uint(f);
  unsigned int r = u + 0x7fffu + ((u >> 16) & 1u);  // RNE
  return (unsigned short)(r >> 16);
}

// ---------------- feats (B,C,P) fp32 -> featsT (B,P,C) bf16 ----------------
__global__ __launch_bounds__(256) void tr_kernel(const float* __restrict__ feats,
                                                 unsigned short* __restrict__ featsT) {
  __shared__ float tile[64][65];
  const int b = blockIdx.y;
  const int p0 = blockIdx.x * 64;
  const int t = threadIdx.x;
  {
    const int pp = t & 63, c4 = t >> 6;
#pragma unroll
    for (int j = 0; j < 16; ++j) {
      int c = j * 4 + c4;
      tile[c][pp] = feats[((size_t)(b * 64 + c)) * 8192 + p0 + pp];
    }
  }
  __syncthreads();
  {
    const int cc = t & 63, p4 = t >> 6;
#pragma unroll
    for (int j = 0; j < 16; ++j) {
      int pr = j * 4 + p4;
      featsT[((size_t)(b * 8192 + p0 + pr)) * 64 + cc] = f2bf(tile[cc][pr]);
    }
  }
}

// ------------- prep: weight pack (bf16, k-contig, pad) + xyzq float4 -------------
__global__ __launch_bounds__(256) void prep_kernel(const float* __restrict__ W1,
                                                   const float* __restrict__ W2,
                                                   const float* __restrict__ Wq1,
                                                   const float* __restrict__ xyz,
                                                   unsigned short* __restrict__ W1p,
                                                   unsigned short* __restrict__ W2p,
                                                   unsigned short* __restrict__ Wq1p,
                                                   float4* __restrict__ xyzq) {
  int i = blockIdx.x * 256 + threadIdx.x;
  if (i < 13312) {  // W1p[128][104]: k<64 feats (W1[o][3+k]), k 64..66 xyz, else 0
    int o = i / 104, k = i % 104;
    float v = 0.f;
    if (k < 64) v = W1[o * 67 + 3 + k];
    else if (k < 67) v = W1[o * 67 + (k - 64)];
    W1p[i] = f2bf(v);
    return;
  }
  i -= 13312;
  if (i < 17408) {  // W2p[128][136]
    int o = i / 136, k = i % 136;
    W2p[i] = (k < 128) ? f2bf(W2[o * 128 + k]) : (unsigned short)0;
    return;
  }
  i -= 17408;
  if (i < 8704) {  // Wq1p[64][136]
    int o = i / 136, k = i % 136;
    Wq1p[i] = (k < 128) ? f2bf(Wq1[o * 128 + k]) : (unsigned short)0;
    return;
  }
  i -= 8704;
  if (i < 32768) {
    const float* q = xyz + (size_t)i * 3;
    float x = q[0], y = q[1], z = q[2];
    float4 v; v.x = x; v.y = y; v.z = z; v.w = (x * x + y * y) + z * z;
    xyzq[i] = v;
  }
}

// ---------------- selection: 512-thr block, 16 points/thread in regs, 16 centers ----------------
// Histogram select on ordered-uint >> 20 (4096 bins); exact tie-break in cutoff bin.
// Waves 1..7 clear the histogram for the next center while wave 0 runs the tie-break.
// NOTE: launch_bounds min-occupancy = 2 (NOT 4): pt[16] needs 64 VGPRs; the
// 4-blocks/CU bound capped VGPRs at 64 and spilled pt[] to scratch (R4 counters:
// FETCH 779 MB, WRITE 360 MB of spill traffic, 317 us). 2 -> >=128 VGPR budget.
#define CANDMAX 512
__global__ __launch_bounds__(512, 2) void sel3_kernel(const float4* __restrict__ xyzq,
    float* __restrict__ centers_out, int* __restrict__ idx_out) {
  const int t = threadIdx.x, lane = t & 63, wid = t >> 6;
  const int b = blockIdx.y;
  const int m0 = blockIdx.x * 16;  // grid.x = 128
  __shared__ unsigned int hist[4096];
  __shared__ unsigned long long cand[CANDMAX];
  __shared__ float4 cc4[16];
  __shared__ int selb[32];
  __shared__ int ctrl[4];
  __shared__ int wsum[8];

  const float4* xb = xyzq + (size_t)b * 8192;
  float4 pt[16];
#pragma unroll
  for (int i = 0; i < 16; ++i) pt[i] = xb[i * 512 + t];

  if (t < 16) {
    int mIdx = m0 + t;
    int pc = (mIdx * 8191) / 2047;  // floor(linspace(0,P-1,M))
    float4 c = xb[pc];
    cc4[t] = c;
    float* co = centers_out + ((size_t)(b * 2048 + mIdx)) * 3;
    co[0] = c.x; co[1] = c.y; co[2] = c.z;
  }
  for (int j = t; j < 4096; j += 512) hist[j] = 0;
  if (t == 0) { ctrl[0] = 0; ctrl[1] = 0; }
  __syncthreads();

  for (int ci = 0; ci < 16; ++ci) {
    const float4 c = cc4[ci];
    // pass 1: histogram
#pragma unroll
    for (int i = 0; i < 16; ++i) {
      float dot = (c.x * pt[i].x + c.y * pt[i].y) + c.z * pt[i].z;
      float d2 = (c.w + pt[i].w) - 2.0f * dot;
      unsigned int u = __float_as_uint(d2);
      u = (u & 0x80000000u) ? ~u : (u | 0x80000000u);
      atomicAdd(&hist[u >> 20], 1u);
    }
    __syncthreads();  // B1
    // block scan over 4096 ordered bins; thread owns bins [t*8, t*8+8)
    const int base = t * 8;
    int csum = 0;
#pragma unroll
    for (int j = 0; j < 8; ++j) csum += (int)hist[base + j];
    int incl = csum;
#pragma unroll
    for (int d = 1; d < 64; d <<= 1) {
      int v = __shfl_up(incl, d);
      if (lane >= d) incl += v;
    }
    if (lane == 63) wsum[wid] = incl;
    __syncthreads();  // B2
    int woff = 0;
    for (int i = 0; i < wid; ++i) woff += wsum[i];
    int excl = woff + incl - csum;
    if (excl < 32 && excl + csum >= 32) {  // unique crossing chunk
      int cum = excl, binsel = base + 7;
      for (int j = 0; j < 8; ++j) {
        int cv = (int)hist[base + j];
        if (cum + cv >= 32) { binsel = base + j; break; }
        cum += cv;
      }
      ctrl[2] = binsel;
    }
    __syncthreads();  // B3
    const unsigned int cutbin = (unsigned int)ctrl[2];
    // pass 2: collect definite picks + cutoff-bin candidates
#pragma unroll
    for (int i = 0; i < 16; ++i) {
      float dot = (c.x * pt[i].x + c.y * pt[i].y) + c.z * pt[i].z;
      float d2 = (c.w + pt[i].w) - 2.0f * dot;
      unsigned int u = __float_as_uint(d2);
      u = (u & 0x80000000u) ? ~u : (u | 0x80000000u);
      unsigned int key = u >> 20;
      if (key < cutbin) {
        int pos = atomicAdd(&ctrl[0], 1);
        selb[pos] = i * 512 + t;
      } else if (key == cutbin) {
        int pos = atomicAdd(&ctrl[1], 1);
        if (pos < CANDMAX) cand[pos] = ((unsigned long long)u << 32) | (unsigned int)(i * 512 + t);
      }
    }
    __syncthreads();  // B4
    if (t < 64) {
      // wave 0: exact tie-break by (d2_bits, idx) ascending
      const int nsel = ctrl[0];
      const int need = 32 - nsel;
      const int nc = min(ctrl[1], CANDMAX);
      volatile unsigned long long* vc = cand;
      for (int r = 0; r < need; ++r) {
        unsigned long long best = ~0ull;
        int bs = -1;
#pragma unroll
        for (int bb = 0; bb < CANDMAX; bb += 64) {
          int j = bb + lane;
          if (j < nc) {
            unsigned long long v = vc[j];
            if (v < best) { best = v; bs = j; }
          }
        }
#pragma unroll
        for (int d = 32; d; d >>= 1) {
          unsigned long long ob = __shfl_xor(best, d);
          int os = __shfl_xor(bs, d);
          if (ob < best) { best = ob; bs = os; }
        }
        if (lane == 0) {
          selb[nsel + r] = (int)(best & 0xffffffffu);
          cand[bs] = ~0ull;
        }
      }
    } else {
      // waves 1..7: clear hist for next center (hist unused by tie-break)
      for (int j = t - 64; j < 4096; j += 448) hist[j] = 0;
    }
    __syncthreads();  // B5
    if (t < 32) idx_out[(size_t)(b * 2048 + m0 + ci) * 32 + t] = selb[t];
    if (t == 0) { ctrl[0] = 0; ctrl[1] = 0; }
    __syncthreads();  // B6
  }
}

// ---------------- cnt/sc scatter + d-moments via LDS (no global float atomics) ----------------
__global__ __launch_bounds__(1024) void cnt_kernel(const float4* __restrict__ xyzq,
    const float* __restrict__ centers, const int* __restrict__ idxb,
    float* __restrict__ cnt, float* __restrict__ scx, float* __restrict__ scy,
    float* __restrict__ scz, float* __restrict__ dstats) {
  const int t = threadIdx.x;
  const int b = blockIdx.x >> 2, quar = blockIdx.x & 3;
  const int pbase = quar * 2048;
  __shared__ float L[4][2048];
  for (int j = t; j < 8192; j += 1024) ((float*)L)[j] = 0.f;
  __syncthreads();
  float m9[9] = {0.f, 0.f, 0.f, 0.f, 0.f, 0.f, 0.f, 0.f, 0.f};
  for (int i = 0; i < 64; ++i) {
    int e = i * 1024 + t;  // (g,k) flat index within batch
    int p = idxb[b * 65536 + e];
    if (p >= pbase && p < pbase + 2048) {
      int g = e >> 5;
      const float* cp = centers + ((size_t)(b * 2048 + g)) * 3;
      float cx = cp[0], cy = cp[1], cz = cp[2];
      float4 v = xyzq[(size_t)b * 8192 + p];
      int l = p - pbase;
      atomicAdd(&L[0][l], 1.f);
      atomicAdd(&L[1][l], cx);
      atomicAdd(&L[2][l], cy);
      atomicAdd(&L[3][l], cz);
      float dx = v.x - cx, dy = v.y - cy, dz = v.z - cz;
      m9[0] += dx; m9[1] += dy; m9[2] += dz;
      m9[3] += dx * dx; m9[4] += dy * dy; m9[5] += dz * dz;
      m9[6] += dx * dy; m9[7] += dx * dz; m9[8] += dy * dz;
    }
  }
#pragma unroll
  for (int k = 0; k < 9; ++k) {
#pragma unroll
    for (int d = 1; d < 64; d <<= 1) m9[k] += __shfl_xor(m9[k], d);
  }
  if ((t & 63) == 0) {
#pragma unroll
    for (int k = 0; k < 9; ++k) atomicAdd(&dstats[k], m9[k]);
  }
  __syncthreads();
  for (int j = t; j < 2048; j += 1024) {
    int gp = b * 8192 + pbase + j;
    cnt[gp] = L[0][j];
    scx[gp] = L[1][j];
    scy[gp] = L[2][j];
    scz[gp] = L[3][j];
  }
}

// ---------------- weighted Gram for analytic BN1 stats ----------------
__global__ __launch_bounds__(256) void gram_kernel(const float* __restrict__ feats,
    const float4* __restrict__ xyzq, const float* __restrict__ cnt,
    const float* __restrict__ scx, const float* __restrict__ scy,
    const float* __restrict__ scz, float* __restrict__ Sff,
    float* __restrict__ Sfd, float* __restrict__ Fbar) {
  const int t = threadIdx.x;
  const int b = blockIdx.y;
  __shared__ float fT[128][68];
  __shared__ float cw_s[128], e_s[3][128];
  const int c1 = (t >> 4) * 4, c2 = (t & 15) * 4;
  const int aux = t & 3;
  const bool doaux = ((t & 15) < 4);
  float acc[4][4] = {};
  float accA[4] = {};
  for (int chunk = 0; chunk < 4; ++chunk) {
    const int p0 = blockIdx.x * 512 + chunk * 128;
    __syncthreads();
#pragma unroll
    for (int j = 0; j < 32; ++j) {
      int idx = j * 256 + t;
      int cch = idx >> 7, pp = idx & 127;
      fT[pp][cch] = feats[((size_t)(b * 64 + cch)) * 8192 + p0 + pp];
    }
    if (t < 128) {
      int gp = b * 8192 + p0 + t;
      float cw = cnt[gp];
      cw_s[t] = cw;
      float4 v = xyzq[gp];
      e_s[0][t] = cw * v.x - scx[gp];
      e_s[1][t] = cw * v.y - scy[gp];
      e_s[2][t] = cw * v.z - scz[gp];
    }
    __syncthreads();
    for (int pp = 0; pp < 128; ++pp) {
      float cw = cw_s[pp];
      float4 f1 = *(const float4*)&fT[pp][c1];
      float4 f2 = *(const float4*)&fT[pp][c2];
      float f1a[4] = {f1.x, f1.y, f1.z, f1.w};
      float f2a[4] = {f2.x, f2.y, f2.z, f2.w};
#pragma unroll
      for (int i = 0; i < 4; ++i) {
        float wsc = f1a[i] * cw;
#pragma unroll
        for (int j = 0; j < 4; ++j) acc[i][j] += wsc * f2a[j];
      }
      if (doaux) {
        float mult = (aux < 3) ? e_s[aux][pp] : cw;
#pragma unroll
        for (int i = 0; i < 4; ++i) accA[i] += f1a[i] * mult;
      }
    }
  }
#pragma unroll
  for (int i = 0; i < 4; ++i)
#pragma unroll
    for (int j = 0; j < 4; ++j) atomicAdd(&Sff[(c1 + i) * 64 + c2 + j], acc[i][j]);
  if (doaux) {
#pragma unroll
    for (int i = 0; i < 4; ++i) {
      if (aux < 3) atomicAdd(&Sfd[(c1 + i) * 3 + aux], accA[i]);
      else atomicAdd(&Fbar[c1 + i], accA[i]);
    }
  }
}

// ---------------- finalize analytic BN1 stats ----------------
__global__ __launch_bounds__(256) void fin_kernel(const float* __restrict__ W1,
    const float* __restrict__ b1, const float* __restrict__ Sff,
    const float* __restrict__ Sfd, const float* __restrict__ Fbar,
    const float* __restrict__ dstats, float* __restrict__ stats) {
  __shared__ float sS[4096], sFd[192], sFb[64], sD[16];
  const int t = threadIdx.x;
  for (int j = t; j < 4096; j += 256) sS[j] = Sff[j];
  if (t < 192) sFd[t] = Sfd[t];
  if (t < 64) sFb[t] = Fbar[t];
  if (t < 9) sD[t] = dstats[t];
  __syncthreads();
  const int c = t >> 1, h = t & 1;
  float wf[64];
#pragma unroll
  for (int i = 0; i < 64; ++i) wf[i] = W1[c * 67 + 3 + i];
  const float wx0 = W1[c * 67], wx1 = W1[c * 67 + 1], wx2 = W1[c * 67 + 2];
  float qacc = 0.f;
  for (int i = h * 32; i < h * 32 + 32; ++i) {
    float rd = 0.f;
    const float4* row = (const float4*)&sS[i * 64];
#pragma unroll
    for (int j4 = 0; j4 < 16; ++j4) {
      float4 v = row[j4];
      rd += v.x * wf[j4 * 4] + v.y * wf[j4 * 4 + 1] + v.z * wf[j4 * 4 + 2] + v.w * wf[j4 * 4 + 3];
    }
    rd += 2.f * (sFd[i * 3] * wx0 + sFd[i * 3 + 1] * wx1 + sFd[i * 3 + 2] * wx2);
    qacc += wf[i] * rd;
  }
  qacc += __shfl_xor(qacc, 1);
  if (h == 0) {
    const float N = 262144.f;
    float lin = 0.f;
#pragma unroll
    for (int i = 0; i < 64; ++i) lin += wf[i] * sFb[i];
    lin += wx0 * sD[0] + wx1 * sD[1] + wx2 * sD[2];
    float bb = b1[c];
    float Sy = lin + bb * N;
    float dd = wx0 * wx0 * sD[3] + wx1 * wx1 * sD[4] + wx2 * wx2 * sD[5]
             + 2.f * (wx0 * wx1 * sD[6] + wx0 * wx2 * sD[7] + wx1 * wx2 * sD[8]);
    float Sy2 = qacc + dd + 2.f * bb * lin + bb * bb * N;
    stats[c] = Sy;
    stats[128 + c] = Sy2;
  }
}

// ---------------- MFMA MLP: STAGE 2 = BN2-stats pass, STAGE 3 = final ----------------
template <int STAGE>
__global__ __launch_bounds__(512) void mlp_kernel(
    const float* __restrict__ xyz, const unsigned short* __restrict__ featsT,
    const int* __restrict__ idxbuf, const float* __restrict__ centers,
    const unsigned short* __restrict__ W1p_g, const float* __restrict__ b1,
    const float* __restrict__ g1, const float* __restrict__ be1,
    const unsigned short* __restrict__ W2p_g, const float* __restrict__ b2,
    const float* __restrict__ g2, const float* __restrict__ be2,
    const unsigned short* __restrict__ Wq1p_g, const float* __restrict__ bq1,
    const float* __restrict__ Wq2, const float* __restrict__ bq2,
    float* __restrict__ stats, float* __restrict__ out_agg) {
  const int t = threadIdx.x;
  const int T = blockIdx.x;
  const int G0 = T * 2;
  const int b = G0 >> 11;

  __shared__ __align__(16) unsigned short R1[13312];  // 26624 B
  __shared__ __align__(16) unsigned short R2h[8704];  // 17408 B
  __shared__ __align__(16) unsigned short R3[8704];   // 17408 B
  __shared__ float sc1a[128], sh1a[128], sc2a[128], sh2a[128];
  float* sredS = (float*)R1;          // stage2 stats overlay (R1 free after G1)
  float* sredQ = (float*)R1 + 512;
  float* sv2 = (float*)R2h;           // stage3 epilogue overlay (R2h free after G2)
  float* wv = (float*)R2h + 128;
  float* agg = (float*)R2h + 192;

  const int lane = t & 63, wid = t >> 6;
  const int m = lane & 15, q = lane >> 4;
  const int rw = wid & 3, cw = wid >> 2;

  // stage W1 -> R1, W2 half0 -> R2h
  for (int i = t; i < 1664; i += 512) ((s16x8*)R1)[i] = ((const s16x8*)W1p_g)[i];
  for (int i = t; i < 1088; i += 512) ((s16x8*)R2h)[i] = ((const s16x8*)W2p_g)[i];

  const float invN = 1.0f / 262144.0f;
  if (t < 128) {
    float mu = stats[t] * invN;
    float var = stats[128 + t] * invN - mu * mu;
    float s = g1[t] * rsqrtf(var + 1e-5f);
    sc1a[t] = s;
    sh1a[t] = (b1[t] - mu) * s + be1[t];
    if (STAGE == 3) {
      float mu2 = stats[256 + t] * invN;
      float var2 = stats[384 + t] * invN - mu2 * mu2;
      float s2 = g2[t] * rsqrtf(var2 + 1e-5f);
      sc2a[t] = s2;
      sh2a[t] = (b2[t] - mu2) * s2 + be2[t];
    }
  }

  // A-frag gather: per-lane direct global loads (issued before b0 to overlap staging)
  const int r = rw * 16 + m;
  const int g = G0 + (r >> 5);
  const int p = idxbuf[(size_t)g * 32 + (r & 31)];
  const unsigned short* fr = featsT + ((size_t)(b * 8192) + p) * 64;
  s16x8 a0 = *(const s16x8*)(fr + q * 8);
  s16x8 a1 = *(const s16x8*)(fr + 32 + q * 8);
  s16x8 a2 = (s16x8){0, 0, 0, 0, 0, 0, 0, 0};
  if (q == 0) {
    const float* cp = centers + (size_t)g * 3;
    const float* qp = xyz + ((size_t)(b * 8192) + p) * 3;
    a2[0] = (short)f2bf(qp[0] - cp[0]);
    a2[1] = (short)f2bf(qp[1] - cp[1]);
    a2[2] = (short)f2bf(qp[2] - cp[2]);
  }
  __syncthreads();  // b0: weights + consts ready

  // ---- G1: 96 -> 128 ----
  f32x4 acc[4];
#pragma unroll
  for (int nt = 0; nt < 4; ++nt) acc[nt] = (f32x4){0.f, 0.f, 0.f, 0.f};
#pragma unroll
  for (int kb = 0; kb < 3; ++kb) {
    s16x8 a = (kb == 0) ? a0 : ((kb == 1) ? a1 : a2);
#pragma unroll
    for (int nt = 0; nt < 4; ++nt) {
      s16x8 bf = *(const s16x8*)(R1 + (cw * 64 + nt * 16 + m) * 104 + kb * 32 + q * 8);
      acc[nt] = __builtin_amdgcn_mfma_f32_16x16x32_bf16(a, bf, acc[nt], 0, 0, 0);
    }
  }
  // BN1+ReLU -> A2 (R3)
#pragma unroll
  for (int nt = 0; nt < 4; ++nt) {
    int ch = cw * 64 + nt * 16 + m;
    float s = sc1a[ch], o = sh1a[ch];
#pragma unroll
    for (int r4 = 0; r4 < 4; ++r4)
      R3[(rw * 16 + q * 4 + r4) * 136 + ch] = f2bf(fmaxf(acc[nt][r4] * s + o, 0.f));
  }
  __syncthreads();  // b1: A2 ready; R1 reads done

  // ---- G2: 128 -> 128 in two 64-col halves ----
  float fl[2][2][4];
  const int aoff2 = (rw * 16 + m) * 136 + q * 8;
  for (int h2 = 0; h2 < 2; ++h2) {
    if (h2 == 1) {
      __syncthreads();  // b2: G2h0's R2h reads done
      for (int i = t; i < 1088; i += 512) ((s16x8*)R2h)[i] = ((const s16x8*)W2p_g)[1088 + i];
      if (STAGE == 3) {
        for (int i = t; i < 1088; i += 512) ((s16x8*)R1)[i] = ((const s16x8*)Wq1p_g)[i];
      }
      __syncthreads();  // b3
    }
    f32x4 bacc[2];
#pragma unroll
    for (int nt = 0; nt < 2; ++nt) bacc[nt] = (f32x4){0.f, 0.f, 0.f, 0.f};
#pragma unroll
    for (int kb = 0; kb < 4; ++kb) {
      s16x8 a = *(const s16x8*)(R3 + aoff2 + kb * 32);
#pragma unroll
      for (int nt = 0; nt < 2; ++nt) {
        s16x8 bf = *(const s16x8*)(R2h + (cw * 32 + nt * 16 + m) * 136 + kb * 32 + q * 8);
        bacc[nt] = __builtin_amdgcn_mfma_f32_16x16x32_bf16(a, bf, bacc[nt], 0, 0, 0);
      }
    }
    if (STAGE == 2) {
#pragma unroll
      for (int nt = 0; nt < 2; ++nt) {
        int chl = cw * 32 + nt * 16 + m;
        float bb = b2[h2 * 64 + chl];
        float s = 0.f, sq = 0.f;
#pragma unroll
        for (int r4 = 0; r4 < 4; ++r4) {
          float y = bacc[nt][r4] + bb;
          s += y; sq += y * y;
        }
        s += __shfl_xor(s, 16); sq += __shfl_xor(sq, 16);
        s += __shfl_xor(s, 32); sq += __shfl_xor(sq, 32);
        if (q == 0) { sredS[chl * 4 + rw] = s; sredQ[chl * 4 + rw] = sq; }
      }
      __syncthreads();
      if (t < 64) {
        float ss = sredS[t * 4] + sredS[t * 4 + 1] + sredS[t * 4 + 2] + sredS[t * 4 + 3];
        float qq = sredQ[t * 4] + sredQ[t * 4 + 1] + sredQ[t * 4 + 2] + sredQ[t * 4 + 3];
        atomicAdd(&stats[256 + h2 * 64 + t], ss);
        atomicAdd(&stats[384 + h2 * 64 + t], qq);
      }
      __syncthreads();
    } else {
#pragma unroll
      for (int nt = 0; nt < 2; ++nt) {
        int ch = h2 * 64 + cw * 32 + nt * 16 + m;
        float s = sc2a[ch], o = sh2a[ch];
#pragma unroll
        for (int r4 = 0; r4 < 4; ++r4)
          fl[h2][nt][r4] = fmaxf(bacc[nt][r4] * s + o, 0.f);
      }
    }
  }
  if (STAGE == 2) return;

  __syncthreads();  // b4: all R3(A2)/R2h reads done
#pragma unroll
  for (int h2 = 0; h2 < 2; ++h2)
#pragma unroll
    for (int nt = 0; nt < 2; ++nt) {
      int ch = h2 * 64 + cw * 32 + nt * 16 + m;
#pragma unroll
      for (int r4 = 0; r4 < 4; ++r4)
        R3[(rw * 16 + q * 4 + r4) * 136 + ch] = f2bf(fl[h2][nt][r4]);
    }
  __syncthreads();  // b5: A3 + Wq1 ready

  // ---- Q: 128 -> 64, ReLU, dot Wq2 -> scores ----
  {
    f32x4 qacc[2];
#pragma unroll
    for (int nt = 0; nt < 2; ++nt) qacc[nt] = (f32x4){0.f, 0.f, 0.f, 0.f};
#pragma unroll
    for (int kb = 0; kb < 4; ++kb) {
      s16x8 a = *(const s16x8*)(R3 + aoff2 + kb * 32);
#pragma unroll
      for (int nt = 0; nt < 2; ++nt) {
        s16x8 bf = *(const s16x8*)(R1 + (cw * 32 + nt * 16 + m) * 136 + kb * 32 + q * 8);
        qacc[nt] = __builtin_amdgcn_mfma_f32_16x16x32_bf16(a, bf, qacc[nt], 0, 0, 0);
      }
    }
    int qc0 = cw * 32 + m, qc1 = qc0 + 16;
    float ba0 = bq1[qc0], ba1 = bq1[qc1];
    float w0 = Wq2[qc0], w1 = Wq2[qc1];
    float part[4];
#pragma unroll
    for (int r4 = 0; r4 < 4; ++r4) {
      float v0 = fmaxf(qacc[0][r4] + ba0, 0.f);
      float v1 = fmaxf(qacc[1][r4] + ba1, 0.f);
      part[r4] = v0 * w0 + v1 * w1;
    }
#pragma unroll
    for (int d = 1; d < 16; d <<= 1) {
#pragma unroll
      for (int r4 = 0; r4 < 4; ++r4) part[r4] += __shfl_xor(part[r4], d);
    }
    if (m == 0) {
#pragma unroll
      for (int r4 = 0; r4 < 4; ++r4) sv2[(rw * 16 + q * 4 + r4) * 2 + cw] = part[r4];
    }
  }
  __syncthreads();  // b6
  if (t < 64) {
    float x = sv2[t * 2] + sv2[t * 2 + 1] + bq2[0];
    float mx = x;
#pragma unroll
    for (int d = 16; d; d >>= 1) mx = fmaxf(mx, __shfl_xor(mx, d, 32));
    float e = expf(x - mx);
    float ssum = e;
#pragma unroll
    for (int d = 16; d; d >>= 1) ssum += __shfl_xor(ssum, d, 32);
    wv[t] = e / ssum;
  }
  __syncthreads();  // b7
  {
    float wreg[4];
#pragma unroll
    for (int r4 = 0; r4 < 4; ++r4) wreg[r4] = wv[rw * 16 + q * 4 + r4];
    const int gl = rw >> 1, rwpar = rw & 1;
#pragma unroll
    for (int h2 = 0; h2 < 2; ++h2)
#pragma unroll
      for (int nt = 0; nt < 2; ++nt) {
        float pv = 0.f;
#pragma unroll
        for (int r4 = 0; r4 < 4; ++r4) pv += wreg[r4] * fl[h2][nt][r4];
        pv += __shfl_xor(pv, 16);
        pv += __shfl_xor(pv, 32);
        if (q == 0) {
          int ch = h2 * 64 + cw * 32 + nt * 16 + m;
          agg[(gl * 128 + ch) * 2 + rwpar] = pv;
        }
      }
  }
  __syncthreads();  // b8
  if (t < 256) {
    int gl = t >> 7, ch = t & 127;
    float v = agg[(gl * 128 + ch) * 2] + agg[(gl * 128 + ch) * 2 + 1];
    out_agg[((size_t)(b * 128 + ch)) * 2048 + ((G0 + gl) & 2047)] = v;
  }
}

extern "C" void kernel_launch(void* const* d_in, const int* in_sizes, int n_in,
                              void* d_out, int out_size, void* d_ws, size_t ws_size,
                              hipStream_t stream) {
  const float* xyz   = (const float*)d_in[0];
  const float* feats = (const float*)d_in[1];
  const float* W1    = (const float*)d_in[2];
  const float* b1    = (const float*)d_in[3];
  const float* g1    = (const float*)d_in[4];
  const float* be1   = (const float*)d_in[5];
  const float* W2    = (const float*)d_in[6];
  const float* b2    = (const float*)d_in[7];
  const float* g2    = (const float*)d_in[8];
  const float* be2   = (const float*)d_in[9];
  const float* Wq1   = (const float*)d_in[10];
  const float* bq1   = (const float*)d_in[11];
  const float* Wq2   = (const float*)d_in[12];
  const float* bq2   = (const float*)d_in[13];

  float* outp    = (float*)d_out;
  float* centers = outp;           // (4,2048,3)
  float* out_agg = outp + 24576;   // (4,128,2048)

  // ws layout (~6.4 MB)
  char* base = (char*)d_ws;
  unsigned short* featsT = (unsigned short*)base;                  // 4,194,304
  float4* xyzq  = (float4*)(base + 4194304);                       //   524,288
  int*    idxb  = (int*)(base + 4718592);                          // 1,048,576
  unsigned short* W1p  = (unsigned short*)(base + 5767168);        //    26,624
  unsigned short* W2p  = (unsigned short*)(base + 5793792);        //    34,816
  unsigned short* Wq1p = (unsigned short*)(base + 5828608);        //    17,408
  float* stats  = (float*)(base + 5846016);   // zero region start (4880 floats)
  float* dstats = stats + 512;
  float* Fbar   = stats + 528;
  float* Sfd    = stats + 592;
  float* Sff    = stats + 784;
  float* cntp   = stats + 4880;               // fully overwritten by cnt_kernel
  float* scx    = cntp + 32768;
  float* scy    = scx + 32768;
  float* scz    = scy + 32768;

  hipMemsetAsync(stats, 0, 19520, stream);
  prep_kernel<<<282, 256, 0, stream>>>(W1, W2, Wq1, xyz, W1p, W2p, Wq1p, xyzq);
  tr_kernel<<<dim3(128, 4), 256, 0, stream>>>(feats, featsT);
  sel3_kernel<<<dim3(128, 4), 512, 0, stream>>>(xyzq, centers, idxb);
  cnt_kernel<<<16, 1024, 0, stream>>>(xyzq, centers, idxb, cntp, scx, scy, scz, dstats);
  gram_kernel<<<dim3(16, 4), 256, 0, stream>>>(feats, xyzq, cntp, scx, scy, scz, Sff, Sfd, Fbar);
  fin_kernel<<<1, 256, 0, stream>>>(W1, b1, Sff, Sfd, Fbar, dstats, stats);
  mlp_kernel<2><<<4096, 512, 0, stream>>>(xyz, featsT, idxb, centers,
                                          W1p, b1, g1, be1, W2p, b2, g2, be2,
                                          Wq1p, bq1, Wq2, bq2, stats, out_agg);
  mlp_kernel<3><<<4096, 512, 0, stream>>>(xyz, featsT, idxb, centers,
                                          W1p, b1, g1, be1, W2p, b2, g2, be2,
                                          Wq1p, bq1, Wq2, bq2, stats, out_agg);
}